// Round 1
// baseline (259.805 us; speedup 1.0000x reference)
//
#include <hip/hip_runtime.h>

// WindowEmbedding forward: out[b,t, w*D+d] = (t-w>=0) ? in[b, t-w, d] : 0
// B=16, T=2048, D=256, W=7.
//
// Round 7: output-centric GATHER (vs rounds 2-6 input-centric scatter).
// Rationale: measured dur (254us) = harness re-poison fill (~148us, shows in
// rocprof at 6.37 TB/s pure-linear-write) + kernel (~106us = 2.5 TB/s
// effective). The scatter assembles each output row's 7KiB from 1-4KiB
// fragments written by different waves/blocks/XCDs -> fragmented write
// stream. Gather gives each block ONE contiguous 112KiB output span
// (fill-shaped linear writes); the 7x read amplification is served by L1/L2
// (22KiB/block input footprint, reused by the block's own 7 waves).
//
// Block = 448 threads = 7 waves; wave w owns window-slot w. Each block does
// RPB=16 consecutive output rows. Per row: wave w loads in[row-w] (1KiB,
// coalesced, L1-warm after first touch) and stores out[row, slot w] (1KiB).
// Batched 16 loads -> 16 stores for ILP. t>=w edge only occurs in blocks at
// a batch start (t0==0): 16 of 2048 blocks take the guarded cold path.

typedef float vf4 __attribute__((ext_vector_type(4)));

constexpr int B    = 16;
constexpr int T    = 2048;
constexpr int D    = 256;
constexpr int W    = 7;
constexpr int D4   = D / 4;        // 64 vec4 per (row, slot) segment = 1 wave
constexpr int ROW4 = W * D4;       // 448 vec4 per output row
constexpr int RPB  = 16;           // rows per block (divides T -> no batch
                                   // boundary inside a block)
constexpr int NROW = B * T;        // 32768 rows
constexpr int NBLK = NROW / RPB;   // 2048 blocks

__global__ __launch_bounds__(W * 64) void window_gather_kernel(
    const vf4* __restrict__ in, vf4* __restrict__ out) {
  const int w  = threadIdx.x >> 6;   // window slot, 0..6 (one wave each)
  const int dd = threadIdx.x & 63;   // vec4 lane within the D-segment
  const int r0 = blockIdx.x * RPB;   // first output row of this block
  const int t0 = r0 & (T - 1);       // within-batch t of first row

  vf4* dst = out + (size_t)r0 * ROW4 + w * D4 + dd;

  if (t0 != 0) {
    // Bulk path (2032/2048 blocks): t0 >= 16 > 6 = W-1, so every row of this
    // block has t >= w for all waves. Unconditional batched load/store.
    const vf4* src = in + (r0 - w) * D4 + dd;
    vf4 v[RPB];
#pragma unroll
    for (int i = 0; i < RPB; ++i) v[i] = src[i * D4];
#pragma unroll
    for (int i = 0; i < RPB; ++i) dst[i * ROW4] = v[i];
  } else {
    // Batch-start blocks: rows i=0..15 have t=i; slot w is zero for i<w.
    // Clamp the source row so the address is always in-bounds, then select.
    vf4 v[RPB];
#pragma unroll
    for (int i = 0; i < RPB; ++i) {
      int sr = r0 + i - w;
      if (sr < 0) sr = 0;                 // safe address for masked lanes
      vf4 ld = in[sr * D4 + dd];
      vf4 z  = {0.f, 0.f, 0.f, 0.f};
      v[i] = (i >= w) ? ld : z;           // wave-uniform select
    }
#pragma unroll
    for (int i = 0; i < RPB; ++i) dst[i * ROW4] = v[i];
  }
}

extern "C" void kernel_launch(void* const* d_in, const int* in_sizes, int n_in,
                              void* d_out, int out_size, void* d_ws, size_t ws_size,
                              hipStream_t stream) {
  const vf4* in = (const vf4*)d_in[0];
  vf4* out = (vf4*)d_out;
  window_gather_kernel<<<NBLK, W * 64, 0, stream>>>(in, out);
}